// Round 10
// baseline (575.338 us; speedup 1.0000x reference)
//
#include <hip/hip_runtime.h>
#include <stdint.h>

#define B_ 8
#define S_ 1024
#define D_ 2048
#define H_ 16
#define HD_ 128
#define NROW 8192      // B_*S_
#define NQKV 6144      // 3*D_

typedef __bf16 bf16;
typedef bf16  bf16x8 __attribute__((ext_vector_type(8)));
typedef bf16  bf16x4 __attribute__((ext_vector_type(4)));
typedef float f32x4  __attribute__((ext_vector_type(4)));

#define AS1 __attribute__((address_space(1)))
#define AS3 __attribute__((address_space(3)))

// async global->LDS, 16B per lane; LDS dest = wave-uniform base + lane*16
__device__ __forceinline__ void gl_lds16(const bf16* g, bf16* l) {
  __builtin_amdgcn_global_load_lds((AS1 void*)g, (AS3 void*)l, 16, 0, 0);
}

// ---------- fused input prep: all fp32->bf16 conversions + bias pack --------
__global__ __launch_bounds__(256) void prep(const float* __restrict__ x,
                                            const float* __restrict__ wq,
                                            const float* __restrict__ wk,
                                            const float* __restrict__ wv,
                                            const float* __restrict__ wo,
                                            const float* __restrict__ mask,
                                            const float* __restrict__ bq,
                                            const float* __restrict__ bk,
                                            const float* __restrict__ bv,
                                            bf16* __restrict__ xb,
                                            bf16* __restrict__ wqkvb,
                                            bf16* __restrict__ wob,
                                            bf16* __restrict__ maskb,
                                            float* __restrict__ bqkv) {
  long i = (long)blockIdx.x * 256 + threadIdx.x;
  if (i < 8650752) {
    const float* src; bf16* dst; long j;
    if (i < 4194304)      { src = x;    dst = xb;              j = i; }
    else if (i < 5242880) { src = wq;   dst = wqkvb;           j = i - 4194304; }
    else if (i < 6291456) { src = wk;   dst = wqkvb + 4194304; j = i - 5242880; }
    else if (i < 7340032) { src = wv;   dst = wqkvb + 8388608; j = i - 6291456; }
    else if (i < 8388608) { src = wo;   dst = wob;             j = i - 7340032; }
    else                  { src = mask; dst = maskb;           j = i - 8388608; }
    float4 v = reinterpret_cast<const float4*>(src)[j];
    bf16x4 o;
    o.x = (bf16)v.x; o.y = (bf16)v.y; o.z = (bf16)v.z; o.w = (bf16)v.w;
    reinterpret_cast<bf16x4*>(dst)[j] = o;
  } else {
    long e = (i - 8650752) * 4;
    const float* s = (e < 2048) ? bq + e : (e < 4096 ? bk + (e - 2048) : bv + (e - 4096));
    *reinterpret_cast<float4*>(bqkv + e) = *reinterpret_cast<const float4*>(s);
  }
}

// =====================================================================
// 256x256 GEMM, m201-style barrier-sandwich 4-phase schedule with r4's
// counted-vmcnt wait algebra: per phase {ds-reads + stage -> barrier ->
// lgkmcnt(0) -> setprio(1) MFMA setprio(0) -> [vmcnt] -> barrier}.
// 8 barriers/tile create per-phase wave role-diversity (T5 gate).
// H0/H1 = kh0/kh1 stage groups (4 gl_lds each per wave).
// P2 closing vmcnt(4): proves H1(t) landed (younger: H0(t+1)).
// P4 closing vmcnt(4): proves H0(t+1) landed (younger: H1(t+1)).
// No vmcnt(0) in steady state; tails drain to 0.
// =====================================================================
#define READ_A4(QA, KS, Ab)                                                   \
  _Pragma("unroll") for (int mi = 0; mi < 4; mi++)                            \
    af[mi] = *reinterpret_cast<const bf16x8*>(                                \
        (Ab) + aoff + ((((QA)*4 + mi)*2) + (KS))*512);

#define READ_B4(KS, Bb)                                                       \
  _Pragma("unroll") for (int ni = 0; ni < 4; ni++)                            \
    bfr[ni] = *reinterpret_cast<const bf16x8*>(                               \
        (Bb) + boff + ((ni*2) + (KS))*512);

#define MFMA16(QA)                                                            \
  _Pragma("unroll") for (int mi = 0; mi < 4; mi++)                            \
  _Pragma("unroll") for (int ni = 0; ni < 4; ni++)                            \
    acc[(QA)*4 + mi][ni] = __builtin_amdgcn_mfma_f32_16x16x32_bf16(           \
        af[mi], bfr[ni], acc[(QA)*4 + mi][ni], 0, 0, 0);

#define STAGE_H0(An, Bn, koff)                                                \
  gl_lds16(agA + (koff),           (An) + wid*1024);                          \
  gl_lds16(agA + 128*la + (koff),  (An) + (wid + 8)*1024);                    \
  gl_lds16(agB + (koff),           (Bn) + wid*1024);                          \
  gl_lds16(agB + 128*lb + (koff),  (Bn) + (wid + 8)*1024);

#define STAGE_H1(An, Bn, koff)                                                \
  gl_lds16(agA + (koff) + 32,          (An) + wid*1024 + 512);                \
  gl_lds16(agA + 128*la + (koff) + 32, (An) + (wid + 8)*1024 + 512);          \
  gl_lds16(agB + (koff) + 32,          (Bn) + wid*1024 + 512);                \
  gl_lds16(agB + 128*lb + (koff) + 32, (Bn) + (wid + 8)*1024 + 512);

// main K-loop body, shared by gemm256 and pv256
#define GEMM256_MAIN_LOOP(NT)                                                 \
  { bf16* An = lds; bf16* Bn = lds + 16384;                                   \
    STAGE_H0(An, Bn, 0); STAGE_H1(An, Bn, 0); }                               \
  asm volatile("s_waitcnt vmcnt(4)" ::: "memory");                            \
  __builtin_amdgcn_s_barrier();                                               \
  for (int t = 0; t < (NT); ++t) {                                            \
    const bf16* Ab = lds + (t & 1) * 32768;                                   \
    const bf16* Bb = Ab + 16384;                                              \
    bf16* An = lds + ((t & 1) ^ 1) * 32768;                                   \
    bf16* Bn = An + 16384;                                                    \
    const long kn = (long)(t + 1) * 64;                                       \
    const bool pf = (t + 1) < (NT);                                           \
    bf16x8 af[4], bfr[4];                                                     \
    /* ---- P1: read kh0 rows-h0 (12 ds); stage H0(t+1) ---- */               \
    __builtin_amdgcn_sched_barrier(0);                                        \
    READ_A4(0, 0, Ab); READ_B4(0, Bb);                                        \
    if (pf) { STAGE_H0(An, Bn, kn); }                                         \
    __builtin_amdgcn_s_barrier();                                             \
    asm volatile("s_waitcnt lgkmcnt(0)" ::: "memory");                        \
    __builtin_amdgcn_sched_barrier(0);                                        \
    __builtin_amdgcn_s_setprio(1); MFMA16(0); __builtin_amdgcn_s_setprio(0);  \
    __builtin_amdgcn_s_barrier();                                             \
    /* ---- P2: read kh0 rows-h1 (8 ds) ---- */                               \
    __builtin_amdgcn_sched_barrier(0);                                        \
    READ_A4(1, 0, Ab);                                                        \
    __builtin_amdgcn_s_barrier();                                             \
    asm volatile("s_waitcnt lgkmcnt(0)" ::: "memory");                        \
    __builtin_amdgcn_sched_barrier(0);                                        \
    __builtin_amdgcn_s_setprio(1); MFMA16(1); __builtin_amdgcn_s_setprio(0);  \
    if (pf) asm volatile("s_waitcnt vmcnt(4)" ::: "memory");                  \
    else    asm volatile("s_waitcnt vmcnt(0)" ::: "memory");                  \
    __builtin_amdgcn_s_barrier();                                             \
    /* ---- P3: read kh1 rows-h0 (12 ds); stage H1(t+1) ---- */               \
    __builtin_amdgcn_sched_barrier(0);                                        \
    READ_A4(0, 1, Ab); READ_B4(1, Bb);                                        \
    if (pf) { STAGE_H1(An, Bn, kn); }                                         \
    __builtin_amdgcn_s_barrier();                                             \
    asm volatile("s_waitcnt lgkmcnt(0)" ::: "memory");                        \
    __builtin_amdgcn_sched_barrier(0);                                        \
    __builtin_amdgcn_s_setprio(1); MFMA16(0); __builtin_amdgcn_s_setprio(0);  \
    __builtin_amdgcn_s_barrier();                                             \
    /* ---- P4: read kh1 rows-h1 (8 ds) ---- */                               \
    __builtin_amdgcn_sched_barrier(0);                                        \
    READ_A4(1, 1, Ab);                                                        \
    __builtin_amdgcn_s_barrier();                                             \
    asm volatile("s_waitcnt lgkmcnt(0)" ::: "memory");                        \
    __builtin_amdgcn_sched_barrier(0);                                        \
    __builtin_amdgcn_s_setprio(1); MFMA16(1); __builtin_amdgcn_s_setprio(0);  \
    if (pf) asm volatile("s_waitcnt vmcnt(4)" ::: "memory");                  \
    else    asm volatile("s_waitcnt vmcnt(0)" ::: "memory");                  \
    __builtin_amdgcn_s_barrier();                                             \
  }

template <typename CT, bool BIAS, bool ACCUM, bool ROPE, int FUSE>
__global__ __launch_bounds__(512, 2) void gemm256(const bf16* __restrict__ A,
                                                  const bf16* __restrict__ Bm,
                                                  const float* __restrict__ bias,
                                                  CT* __restrict__ C,
                                                  int M, int N, int K,
                                                  long la, long lb, long lc,
                                                  long za, long zb, long zc,
                                                  const float* __restrict__ chp,
                                                  const float* __restrict__ shp,
                                                  bf16* __restrict__ Kt,
                                                  bf16* __restrict__ Vt) {
  extern __shared__ __align__(16) bf16 lds[];   // 65536 elems = 128 KiB
  const int z = blockIdx.z;
  A  += (long)z * za;
  Bm += (long)z * zb;
  C  += (long)z * zc;
  const int tid  = threadIdx.x;
  const int wid  = tid >> 6;
  const int lane = tid & 63;
  const int wm0 = (wid >> 2) * 128;
  const int wn0 = (wid & 3) * 64;
  const int m0 = blockIdx.y * 256, n0 = blockIdx.x * 256;

  const int rr = lane >> 2;
  const int cc = ((lane & 3) * 8) ^ ((rr & 8) << 1);
  const bf16* agA = A  + (long)(m0 + wid * 16 + rr) * la + cc;
  const bf16* agB = Bm + (long)(n0 + wid * 16 + rr) * lb + cc;

  const int swz  = ((lane >> 4) * 8) ^ ((lane & 8) << 1);
  const int aoff = (wm0 >> 4) * 1024 + (lane & 15) * 32 + swz;
  const int boff = (wn0 >> 4) * 1024 + (lane & 15) * 32 + swz;

  f32x4 acc[8][4] = {};
  const int NT = K >> 6;

  GEMM256_MAIN_LOOP(NT);

  const bool doRope = ROPE && (((n0 + wn0) & 127) == 0) && ((n0 + wn0) < 4096);

  if (FUSE == 1 && n0 >= 2048) {
    // ---------- K/V region: bias(+RoPE) then in-LDS transpose -> Kt/Vt ----
    const int breg = m0 >> 10;         // batch
    const int t0   = m0 & 1023;        // t base within batch
    const int relc = n0 & 2047;        // region-relative col base
    bf16* XT = (n0 < 4096) ? Kt : Vt;
    __builtin_amdgcn_s_barrier();      // all waves done with main-loop LDS
#pragma unroll
    for (int st = 0; st < 2; ++st) {
#pragma unroll
      for (int mi2 = 0; mi2 < 4; mi2++) {
        const int mi = st * 4 + mi2;
        float vals[4][4];
#pragma unroll
        for (int ni = 0; ni < 4; ni++) {
          const int col = n0 + wn0 + ni * 16 + (lane & 15);
          float bv = 0.0f;
          if constexpr (BIAS) bv = bias[col];
#pragma unroll
          for (int r = 0; r < 4; r++) vals[ni][r] = acc[mi][ni][r] + bv;
        }
        if (doRope) {
#pragma unroll
          for (int ni = 0; ni < 2; ni++)
#pragma unroll
            for (int r = 0; r < 4; r++) {
              const int srow = (m0 + wm0 + mi * 16 + (lane >> 4) * 4 + r) & (S_ - 1);
              const int hd = ni * 16 + (lane & 15);
              const float c  = chp[srow * 32 + hd];
              const float sn = shp[srow * 32 + hd];
              const float a  = vals[ni][r], b2 = vals[ni + 2][r];
              vals[ni][r]     = a * c - b2 * sn;
              vals[ni + 2][r] = b2 * c + a * sn;
            }
        }
#pragma unroll
        for (int ni = 0; ni < 4; ni++) {
          const int col_l = wn0 + ni * 16 + (lane & 15);
          const int row_l = wm0 + mi * 16 + ((lane >> 4) << 2);
          const int pr = (row_l & 63) | ((row_l & 128) >> 1);   // packed row
          bf16x4 o;
          o.x = (bf16)vals[ni][0]; o.y = (bf16)vals[ni][1];
          o.z = (bf16)vals[ni][2]; o.w = (bf16)vals[ni][3];
          *reinterpret_cast<bf16x4*>(
              lds + col_l * 128 + (pr ^ ((col_l & 7) << 3))) = o;
        }
      }
      asm volatile("s_waitcnt lgkmcnt(0)" ::: "memory");
      __builtin_amdgcn_s_barrier();
#pragma unroll
      for (int it = 0; it < 8; ++it) {
        const int idx = it * 512 + tid;
        const int colg = idx >> 4;             // 0..255 (2 heads x 128 hd)
        const int tp8  = (idx & 15) * 8;       // packed-row group
        bf16x8 v = *reinterpret_cast<const bf16x8*>(
            lds + colg * 128 + (tp8 ^ ((colg & 7) << 3)));
        const int trow = (tp8 & 63) + ((tp8 >> 6) << 7) + st * 64;
        const int bh = breg * 16 + (relc >> 7) + (colg >> 7);
        *reinterpret_cast<bf16x8*>(
            XT + (long)bh * (HD_ * S_) + (colg & 127) * S_ + t0 + trow) = v;
      }
      if (st == 0) {
        asm volatile("s_waitcnt lgkmcnt(0)" ::: "memory");
        __builtin_amdgcn_s_barrier();
      }
    }
    return;
  }

  // ---------- normal epilogue (Q region / plain GEMM) ----------
#pragma unroll
  for (int mi = 0; mi < 8; mi++) {
    float vals[4][4];
#pragma unroll
    for (int ni = 0; ni < 4; ni++) {
      const int col = n0 + wn0 + ni * 16 + (lane & 15);
      float bv = 0.0f;
      if constexpr (BIAS) bv = bias[col];
#pragma unroll
      for (int r = 0; r < 4; r++) vals[ni][r] = acc[mi][ni][r] + bv;
    }
    if constexpr (ROPE) {
      if (doRope) {
#pragma unroll
        for (int ni = 0; ni < 2; ni++)
#pragma unroll
          for (int r = 0; r < 4; r++) {
            const int srow = (m0 + wm0 + mi * 16 + (lane >> 4) * 4 + r) & (S_ - 1);
            const int hd = ni * 16 + (lane & 15);
            const float c  = chp[srow * 32 + hd];
            const float sn = shp[srow * 32 + hd];
            const float a  = vals[ni][r], b2 = vals[ni + 2][r];
            vals[ni][r]     = a * c - b2 * sn;
            vals[ni + 2][r] = b2 * c + a * sn;
          }
      }
    }
#pragma unroll
    for (int ni = 0; ni < 4; ni++) {
      const int col = n0 + wn0 + ni * 16 + (lane & 15);
      const long base = (long)(m0 + wm0 + mi * 16 + (lane >> 4) * 4) * lc + col;
#pragma unroll
      for (int r = 0; r < 4; r++) {
        float v = vals[ni][r];
        if constexpr (ACCUM) v += (float)C[base + (long)r * lc];
        C[base + (long)r * lc] = (CT)v;
      }
    }
  }
}

// =====================================================================
// pv256: Ob[b] = mask @ V_b  (K=1024 main loop)  +  Q_b @ W2_b^T (K2=128
// tail fused). Grid (8,4,8): x=col tile, y=row tile, z=b.
// =====================================================================
__global__ __launch_bounds__(512, 2) void pv256(const bf16* __restrict__ Am,
                                                const bf16* __restrict__ Vt,
                                                const bf16* __restrict__ QKV,
                                                const bf16* __restrict__ W2,
                                                bf16* __restrict__ Ob) {
  extern __shared__ __align__(16) bf16 lds[];
  const int z = blockIdx.z;                    // batch b
  const bf16* A  = Am;                         // mask (shared over b)
  const bf16* Bm = Vt + (long)z * (D_ * S_);
  bf16* C = Ob + (long)z * (S_ * D_);
  const long la = S_, lb = S_;
  const int tid  = threadIdx.x;
  const int wid  = tid >> 6;
  const int lane = tid & 63;
  const int wm0 = (wid >> 2) * 128;
  const int wn0 = (wid & 3) * 64;
  const int m0 = blockIdx.y * 256, n0 = blockIdx.x * 256;

  const int rr = lane >> 2;
  const int cc = ((lane & 3) * 8) ^ ((rr & 8) << 1);
  const bf16* agA = A  + (long)(m0 + wid * 16 + rr) * la + cc;
  const bf16* agB = Bm + (long)(n0 + wid * 16 + rr) * lb + cc;

  const int swz  = ((lane >> 4) * 8) ^ ((lane & 8) << 1);
  const int aoff = (wm0 >> 4) * 1024 + (lane & 15) * 32 + swz;
  const int boff = (wn0 >> 4) * 1024 + (lane & 15) * 32 + swz;

  f32x4 acc[8][4] = {};

  GEMM256_MAIN_LOOP(16);

  // ---------------- K2 tail: acc += Q[.,h*128+e] * W2[h][d][e]^T ----------
  const int h0 = n0 >> 7;
  const int hsel = wn0 >> 7;
  const int a2base = hsel * 16384;
  const int b2base = 32768 + hsel * 8192;
  const int bsub = (wn0 & 64) >> 4;
  const int a2off = (wm0 >> 4) * 1024 + (lane & 15) * 32 + swz;
  const int b2off = (lane & 15) * 32 + swz;

#define STAGE_K2(e0)                                                          \
  { const bf16* qa0 = QKV + (long)(z * S_ + m0 + wid * 16 + rr) * NQKV        \
                      + h0 * 128 + (e0) + cc;                                 \
    gl_lds16(qa0,                       lds + wid * 1024);                    \
    gl_lds16(qa0 + 32,                  lds + wid * 1024 + 512);              \
    gl_lds16(qa0 + 128 * NQKV,          lds + (wid + 8) * 1024);              \
    gl_lds16(qa0 + 128 * NQKV + 32,     lds + (wid + 8) * 1024 + 512);        \
    gl_lds16(qa0 + 128,                 lds + 16384 + wid * 1024);            \
    gl_lds16(qa0 + 160,                 lds + 16384 + wid * 1024 + 512);      \
    gl_lds16(qa0 + 128 * NQKV + 128,    lds + 16384 + (wid + 8) * 1024);      \
    gl_lds16(qa0 + 128 * NQKV + 160,    lds + 16384 + (wid + 8) * 1024 + 512);\
    const bf16* w0 = W2 + (long)(z * 16 + h0) * 16384                         \
                     + (wid * 16 + rr) * 128 + (e0) + cc;                     \
    gl_lds16(w0,                        lds + 32768 + wid * 1024);            \
    gl_lds16(w0 + 32,                   lds + 32768 + wid * 1024 + 512);      \
    gl_lds16(w0 + 16384,                lds + 40960 + wid * 1024);            \
    gl_lds16(w0 + 16384 + 32,           lds + 40960 + wid * 1024 + 512);      }

  __builtin_amdgcn_s_barrier();
  STAGE_K2(0);
#pragma unroll
  for (int step = 0; step < 2; step++) {
    asm volatile("s_waitcnt vmcnt(0)" ::: "memory");
    __builtin_amdgcn_s_barrier();
    __builtin_amdgcn_sched_barrier(0);
    bf16x8 a2[8], b2[4];
#pragma unroll
    for (int ks = 0; ks < 2; ks++) {
#pragma unroll
      for (int mi = 0; mi < 8; mi++)
        a2[mi] = *reinterpret_cast<const bf16x8*>(
            lds + a2base + a2off + mi * 1024 + ks * 512);
#pragma unroll
      for (int ni = 0; ni < 4; ni++)
        b2[ni] = *reinterpret_cast<const bf16x8*>(
            lds + b2base + b2off + (bsub + ni) * 1024 + ks * 512);
      __builtin_amdgcn_s_setprio(1);
#pragma unroll
      for (int mi = 0; mi < 8; mi++)
#pragma unroll
        for (int ni = 0; ni < 4; ni++)
          acc[mi][ni] = __builtin_amdgcn_mfma_f32_16x16x32_bf16(
              a2[mi], b2[ni], acc[mi][ni], 0, 0, 0);
      __builtin_amdgcn_s_setprio(0);
    }
    if (step == 0) {
      asm volatile("s_waitcnt lgkmcnt(0)" ::: "memory");
      __builtin_amdgcn_s_barrier();
      STAGE_K2(64);
    }
  }
#undef STAGE_K2

#pragma unroll
  for (int mi = 0; mi < 8; mi++) {
#pragma unroll
    for (int ni = 0; ni < 4; ni++) {
      const int col = n0 + wn0 + ni * 16 + (lane & 15);
      const long base = (long)(m0 + wm0 + mi * 16 + (lane >> 4) * 4) * D_ + col;
#pragma unroll
      for (int r = 0; r < 4; r++)
        C[base + (long)r * D_] = (bf16)acc[mi][ni][r];
    }
  }
}

// ---------- m97-style 128^2 GEMM (kept for small shapes: W2) ----------
template <typename CT, bool BIAS, bool ACCUM>
__global__ __launch_bounds__(256) void gemm_bt(const bf16* __restrict__ A,
                                               const bf16* __restrict__ Bm,
                                               const float* __restrict__ bias,
                                               CT* __restrict__ C,
                                               int M, int N, int K,
                                               long la, long lb, long lc,
                                               long za, long zb, long zc) {
  __shared__ __align__(16) bf16 As[128 * 32];
  __shared__ __align__(16) bf16 Bs[128 * 32];
  const int z = blockIdx.z;
  A  += (long)z * za;
  Bm += (long)z * zb;
  C  += (long)z * zc;
  const int tid = threadIdx.x;
  const int w = tid >> 6, l = tid & 63;
  const int wm = (w & 1) * 64, wn = (w >> 1) * 64;
  const int m0 = blockIdx.y * 128, n0 = blockIdx.x * 128;
  const int lr = l & 15, lk = (l >> 4) * 8;
  const int er = (l >> 4) * 4;

  const bf16* ag = A  + (long)(m0 + (tid >> 2)) * la + (tid & 3) * 8;
  const bf16* bg = Bm + (long)(n0 + (tid >> 2)) * lb + (tid & 3) * 8;
  bf16* al = As + (w * 16) * 32;
  bf16* bl = Bs + (w * 16) * 32;

  f32x4 acc[4][4] = {};

  for (int k0 = 0; k0 < K; k0 += 32) {
    gl_lds16(ag + k0,            al);
    gl_lds16(ag + 64 * la + k0,  al + 64 * 32);
    gl_lds16(bg + k0,            bl);
    gl_lds16(bg + 64 * lb + k0,  bl + 64 * 32);
    __syncthreads();
    bf16x8 afr[4], bfr[4];
#pragma unroll
    for (int mi = 0; mi < 4; mi++)
      afr[mi] = *reinterpret_cast<const bf16x8*>(As + (wm + mi * 16 + lr) * 32 + lk);
#pragma unroll
    for (int ni = 0; ni < 4; ni++)
      bfr[ni] = *reinterpret_cast<const bf16x8*>(Bs + (wn + ni * 16 + lr) * 32 + lk);
#pragma unroll
    for (int mi = 0; mi < 4; mi++)
#pragma unroll
      for (int ni = 0; ni < 4; ni++)
        acc[mi][ni] = __builtin_amdgcn_mfma_f32_16x16x32_bf16(afr[mi], bfr[ni], acc[mi][ni], 0, 0, 0);
    __syncthreads();
  }

#pragma unroll
  for (int mi = 0; mi < 4; mi++) {
#pragma unroll
    for (int ni = 0; ni < 4; ni++) {
      const int col = n0 + wn + ni * 16 + lr;
      float bv = 0.0f;
      if constexpr (BIAS) bv = bias[col];
      const long base = (long)(m0 + wm + mi * 16 + er) * lc + col;
#pragma unroll
      for (int r = 0; r < 4; r++) {
        float v = acc[mi][ni][r] + bv;
        if constexpr (ACCUM) v += (float)C[base + (long)r * lc];
        C[base + (long)r * lc] = (CT)v;
      }
    }
  }
}

extern "C" void kernel_launch(void* const* d_in, const int* in_sizes, int n_in,
                              void* d_out, int out_size, void* d_ws, size_t ws_size,
                              hipStream_t stream) {
  const float* x   = (const float*)d_in[0];
  const float* wq  = (const float*)d_in[1];
  const float* bq  = (const float*)d_in[2];
  const float* wk  = (const float*)d_in[3];
  const float* bk  = (const float*)d_in[4];
  const float* wv  = (const float*)d_in[5];
  const float* bv  = (const float*)d_in[6];
  const float* wo  = (const float*)d_in[7];
  const float* bo  = (const float*)d_in[8];
  const float* ch  = (const float*)d_in[9];
  const float* sh  = (const float*)d_in[10];
  const float* mask = (const float*)d_in[11];
  float* out = (float*)d_out;

  // allow 128 KiB dynamic LDS for the 256^2 kernels
  hipFuncSetAttribute(reinterpret_cast<const void*>(&gemm256<bf16, true, false, true, 1>),
                      hipFuncAttributeMaxDynamicSharedMemorySize, 131072);
  hipFuncSetAttribute(reinterpret_cast<const void*>(&gemm256<float, true, false, false, 0>),
                      hipFuncAttributeMaxDynamicSharedMemorySize, 131072);
  hipFuncSetAttribute(reinterpret_cast<const void*>(&pv256),
                      hipFuncAttributeMaxDynamicSharedMemorySize, 131072);

  char* ws = (char*)d_ws;
  bf16*  QKV   = (bf16*)(ws);                    // 96 MB (only Q region written)
  bf16*  Vt    = (bf16*)(ws + 100663296);        // 32 MB
  bf16*  Kt    = (bf16*)(ws + 134217728);        // 32 MB
  bf16*  wob   = (bf16*)(ws + 167772160);        // 8 MB
  float* bqkv  = (float*)(ws + 176160768);       // 24 KB
  bf16*  maskb = (bf16*)(ws + 176185344);        // 2 MB
  bf16*  W2    = (bf16*)(ws + 178282496);        // 4 MB
  bf16*  Ob    = (bf16*)(ws + 182476800);        // 32 MB
  bf16*  xb    = (bf16*)(ws + 216031232);        // 32 MB (dead after GEMM1)
  bf16*  wqkvb = (bf16*)(ws + 249585664);        // 24 MB (dead after GEMM1)

  // fused conversions + bias pack
  prep<<<33798, 256, 0, stream>>>(x, wq, wk, wv, wo, mask, bq, bk, bv,
                                  xb, wqkvb, wob, maskb, bqkv);

  // QKV projection + RoPE + fused K/V transpose:
  //   Q region -> QKV (roped); K -> Kt (roped, transposed); V -> Vt
  gemm256<bf16, true, false, true, 1><<<dim3(24, 32, 1), 512, 131072, stream>>>(
      xb, wqkvb, bqkv, QKV, NROW, NQKV, D_,
      (long)D_, (long)D_, (long)NQKV, 0L, 0L, 0L, ch, sh, Kt, Vt);

  // W2[bh][d][e] = sum_t V[t,d] K[t,e]   (128 batches of 128x128xK=1024)
  gemm_bt<bf16, false, false><<<dim3(1, 1, 128), 256, 0, stream>>>(
      Vt, Kt, nullptr, W2, HD_, HD_, S_,
      (long)S_, (long)S_, (long)HD_,
      (long)(HD_ * S_), (long)(HD_ * S_), (long)(HD_ * HD_));

  // Ob = mask @ V + Q @ W2^T  (fused; 8 batches of 1024 x 2048)
  pv256<<<dim3(8, 4, 8), 512, 131072, stream>>>(maskb, Vt, QKV, W2, Ob);

  // out = a_sum @ wo^T + bo  (8192 x 2048 x 2048, fp32 output)
  gemm256<float, true, false, false, 0><<<dim3(8, 32, 1), 512, 131072, stream>>>(
      Ob, wob, bo, out, NROW, D_, D_,
      (long)D_, (long)D_, (long)D_, 0L, 0L, 0L, nullptr, nullptr, nullptr, nullptr);
}

// Round 11
// 541.911 us; speedup vs baseline: 1.0617x; 1.0617x over previous
//
#include <hip/hip_runtime.h>
#include <stdint.h>

#define B_ 8
#define S_ 1024
#define D_ 2048
#define H_ 16
#define HD_ 128
#define NROW 8192      // B_*S_
#define NQKV 6144      // 3*D_

typedef __bf16 bf16;
typedef bf16  bf16x8 __attribute__((ext_vector_type(8)));
typedef bf16  bf16x4 __attribute__((ext_vector_type(4)));
typedef float f32x4  __attribute__((ext_vector_type(4)));

#define AS1 __attribute__((address_space(1)))
#define AS3 __attribute__((address_space(3)))

// async global->LDS, 16B per lane; LDS dest = wave-uniform base + lane*16
__device__ __forceinline__ void gl_lds16(const bf16* g, bf16* l) {
  __builtin_amdgcn_global_load_lds((AS1 void*)g, (AS3 void*)l, 16, 0, 0);
}

// ---------- flag init (mask-nonzero detector) ----------
__global__ void initflag(int* __restrict__ f) { *f = 0; }

// ---------- fused input prep: all fp32->bf16 conversions + bias pack --------
__global__ __launch_bounds__(256) void prep(const float* __restrict__ x,
                                            const float* __restrict__ wq,
                                            const float* __restrict__ wk,
                                            const float* __restrict__ wv,
                                            const float* __restrict__ wo,
                                            const float* __restrict__ mask,
                                            const float* __restrict__ bq,
                                            const float* __restrict__ bk,
                                            const float* __restrict__ bv,
                                            bf16* __restrict__ xb,
                                            bf16* __restrict__ wqkvb,
                                            bf16* __restrict__ wob,
                                            bf16* __restrict__ maskb,
                                            float* __restrict__ bqkv,
                                            int* __restrict__ mnz) {
  long i = (long)blockIdx.x * 256 + threadIdx.x;
  if (i < 8650752) {
    const float* src; bf16* dst; long j;
    bool ismask = false;
    if (i < 4194304)      { src = x;    dst = xb;              j = i; }
    else if (i < 5242880) { src = wq;   dst = wqkvb;           j = i - 4194304; }
    else if (i < 6291456) { src = wk;   dst = wqkvb + 4194304; j = i - 5242880; }
    else if (i < 7340032) { src = wv;   dst = wqkvb + 8388608; j = i - 6291456; }
    else if (i < 8388608) { src = wo;   dst = wob;             j = i - 7340032; }
    else                  { src = mask; dst = maskb;           j = i - 8388608; ismask = true; }
    float4 v = reinterpret_cast<const float4*>(src)[j];
    bf16x4 o;
    o.x = (bf16)v.x; o.y = (bf16)v.y; o.z = (bf16)v.z; o.w = (bf16)v.w;
    reinterpret_cast<bf16x4*>(dst)[j] = o;
    if (ismask) {
      // mask segment blocks are fully populated (boundaries 256-aligned),
      // so wave-vote is safe here.
      bool nz = (v.x != 0.f) | (v.y != 0.f) | (v.z != 0.f) | (v.w != 0.f);
      if (__any(nz) && (threadIdx.x & 63) == 0) atomicOr(mnz, 1);
    }
  } else {
    long e = (i - 8650752) * 4;
    const float* s = (e < 2048) ? bq + e : (e < 4096 ? bk + (e - 2048) : bv + (e - 4096));
    *reinterpret_cast<float4*>(bqkv + e) = *reinterpret_cast<const float4*>(s);
  }
}

// =====================================================================
// 256x256 GEMM, r4 counted-vmcnt wait/stage structure, unpinned phases
// (best measured: r9, e2e 566.4us). H0/H1 = kh0/kh1 stage groups
// (4 gl_lds each per wave). P1: vmcnt(4) [H0(t) landed], stage H0(t+1).
// P3: vmcnt(4) [H1(t) landed], stage H1(t+1). 2 barriers/tile; no
// vmcnt(0) in steady state. sched_barrier(0) right after each s_barrier
// (reads must not slip between barrier and co-wave drains).
// =====================================================================
#define READ_A4(QA, KS, Ab)                                                   \
  _Pragma("unroll") for (int mi = 0; mi < 4; mi++)                            \
    af[mi] = *reinterpret_cast<const bf16x8*>(                                \
        (Ab) + aoff + ((((QA)*4 + mi)*2) + (KS))*512);

#define READ_B4(KS, Bb)                                                       \
  _Pragma("unroll") for (int ni = 0; ni < 4; ni++)                            \
    bfr[ni] = *reinterpret_cast<const bf16x8*>(                               \
        (Bb) + boff + ((ni*2) + (KS))*512);

#define MFMA16(QA)                                                            \
  _Pragma("unroll") for (int mi = 0; mi < 4; mi++)                            \
  _Pragma("unroll") for (int ni = 0; ni < 4; ni++)                            \
    acc[(QA)*4 + mi][ni] = __builtin_amdgcn_mfma_f32_16x16x32_bf16(           \
        af[mi], bfr[ni], acc[(QA)*4 + mi][ni], 0, 0, 0);

#define STAGE_H0(An, Bn, koff)                                                \
  gl_lds16(agA + (koff),           (An) + wid*1024);                          \
  gl_lds16(agA + 128*la + (koff),  (An) + (wid + 8)*1024);                    \
  gl_lds16(agB + (koff),           (Bn) + wid*1024);                          \
  gl_lds16(agB + 128*lb + (koff),  (Bn) + (wid + 8)*1024);

#define STAGE_H1(An, Bn, koff)                                                \
  gl_lds16(agA + (koff) + 32,          (An) + wid*1024 + 512);                \
  gl_lds16(agA + 128*la + (koff) + 32, (An) + (wid + 8)*1024 + 512);          \
  gl_lds16(agB + (koff) + 32,          (Bn) + wid*1024 + 512);                \
  gl_lds16(agB + 128*lb + (koff) + 32, (Bn) + (wid + 8)*1024 + 512);

// main K-loop body, shared by gemm256 and pv256
#define GEMM256_MAIN_LOOP(NT)                                                 \
  { bf16* An = lds; bf16* Bn = lds + 16384;                                   \
    STAGE_H0(An, Bn, 0); STAGE_H1(An, Bn, 0); }                               \
  for (int t = 0; t < (NT); ++t) {                                            \
    const bf16* Ab = lds + (t & 1) * 32768;                                   \
    const bf16* Bb = Ab + 16384;                                              \
    bf16* An = lds + ((t & 1) ^ 1) * 32768;                                   \
    bf16* Bn = An + 16384;                                                    \
    const long kn = (long)(t + 1) * 64;                                       \
    const bool pf = (t + 1) < (NT);                                           \
    bf16x8 af[4], bfr[4];                                                     \
    asm volatile("s_waitcnt vmcnt(4)" ::: "memory");                          \
    __builtin_amdgcn_s_barrier();                                             \
    __builtin_amdgcn_sched_barrier(0);                                        \
    READ_A4(0, 0, Ab); READ_B4(0, Bb);                                        \
    if (pf) { STAGE_H0(An, Bn, kn); }                                         \
    __builtin_amdgcn_s_setprio(1); MFMA16(0); __builtin_amdgcn_s_setprio(0);  \
    READ_A4(1, 0, Ab);                                                        \
    __builtin_amdgcn_s_setprio(1); MFMA16(1); __builtin_amdgcn_s_setprio(0);  \
    if (pf) asm volatile("s_waitcnt vmcnt(4)" ::: "memory");                  \
    else    asm volatile("s_waitcnt vmcnt(0)" ::: "memory");                  \
    __builtin_amdgcn_s_barrier();                                             \
    __builtin_amdgcn_sched_barrier(0);                                        \
    READ_A4(0, 1, Ab); READ_B4(1, Bb);                                        \
    if (pf) { STAGE_H1(An, Bn, kn); }                                         \
    __builtin_amdgcn_s_setprio(1); MFMA16(0); __builtin_amdgcn_s_setprio(0);  \
    READ_A4(1, 1, Ab);                                                        \
    __builtin_amdgcn_s_setprio(1); MFMA16(1); __builtin_amdgcn_s_setprio(0);  \
  }

template <typename CT, bool BIAS, bool ACCUM, bool ROPE, int FUSE>
__global__ __launch_bounds__(512, 2) void gemm256(const bf16* __restrict__ A,
                                                  const bf16* __restrict__ Bm,
                                                  const float* __restrict__ bias,
                                                  CT* __restrict__ C,
                                                  int M, int N, int K,
                                                  long la, long lb, long lc,
                                                  long za, long zb, long zc,
                                                  const float* __restrict__ chp,
                                                  const float* __restrict__ shp,
                                                  bf16* __restrict__ Kt,
                                                  bf16* __restrict__ Vt) {
  extern __shared__ __align__(16) bf16 lds[];   // 65536 elems = 128 KiB
  const int z = blockIdx.z;
  A  += (long)z * za;
  Bm += (long)z * zb;
  C  += (long)z * zc;
  const int tid  = threadIdx.x;
  const int wid  = tid >> 6;
  const int lane = tid & 63;
  const int wm0 = (wid >> 2) * 128;
  const int wn0 = (wid & 3) * 64;
  const int m0 = blockIdx.y * 256, n0 = blockIdx.x * 256;

  const int rr = lane >> 2;
  const int cc = ((lane & 3) * 8) ^ ((rr & 8) << 1);
  const bf16* agA = A  + (long)(m0 + wid * 16 + rr) * la + cc;
  const bf16* agB = Bm + (long)(n0 + wid * 16 + rr) * lb + cc;

  const int swz  = ((lane >> 4) * 8) ^ ((lane & 8) << 1);
  const int aoff = (wm0 >> 4) * 1024 + (lane & 15) * 32 + swz;
  const int boff = (wn0 >> 4) * 1024 + (lane & 15) * 32 + swz;

  f32x4 acc[8][4] = {};
  const int NT = K >> 6;

  GEMM256_MAIN_LOOP(NT);

  const bool doRope = ROPE && (((n0 + wn0) & 127) == 0) && ((n0 + wn0) < 4096);

  if (FUSE == 1 && n0 >= 2048) {
    // ---------- K/V region: bias(+RoPE) then in-LDS transpose -> Kt/Vt ----
    const int breg = m0 >> 10;         // batch
    const int t0   = m0 & 1023;        // t base within batch
    const int relc = n0 & 2047;        // region-relative col base
    bf16* XT = (n0 < 4096) ? Kt : Vt;
    __builtin_amdgcn_s_barrier();      // all waves done with main-loop LDS
#pragma unroll
    for (int st = 0; st < 2; ++st) {
#pragma unroll
      for (int mi2 = 0; mi2 < 4; mi2++) {
        const int mi = st * 4 + mi2;
        float vals[4][4];
#pragma unroll
        for (int ni = 0; ni < 4; ni++) {
          const int col = n0 + wn0 + ni * 16 + (lane & 15);
          float bv = 0.0f;
          if constexpr (BIAS) bv = bias[col];
#pragma unroll
          for (int r = 0; r < 4; r++) vals[ni][r] = acc[mi][ni][r] + bv;
        }
        if (doRope) {
#pragma unroll
          for (int ni = 0; ni < 2; ni++)
#pragma unroll
            for (int r = 0; r < 4; r++) {
              const int srow = (m0 + wm0 + mi * 16 + (lane >> 4) * 4 + r) & (S_ - 1);
              const int hd = ni * 16 + (lane & 15);
              const float c  = chp[srow * 32 + hd];
              const float sn = shp[srow * 32 + hd];
              const float a  = vals[ni][r], b2 = vals[ni + 2][r];
              vals[ni][r]     = a * c - b2 * sn;
              vals[ni + 2][r] = b2 * c + a * sn;
            }
        }
#pragma unroll
        for (int ni = 0; ni < 4; ni++) {
          const int col_l = wn0 + ni * 16 + (lane & 15);
          const int row_l = wm0 + mi * 16 + ((lane >> 4) << 2);
          const int pr = (row_l & 63) | ((row_l & 128) >> 1);   // packed row
          bf16x4 o;
          o.x = (bf16)vals[ni][0]; o.y = (bf16)vals[ni][1];
          o.z = (bf16)vals[ni][2]; o.w = (bf16)vals[ni][3];
          *reinterpret_cast<bf16x4*>(
              lds + col_l * 128 + (pr ^ ((col_l & 7) << 3))) = o;
        }
      }
      asm volatile("s_waitcnt lgkmcnt(0)" ::: "memory");
      __builtin_amdgcn_s_barrier();
#pragma unroll
      for (int it = 0; it < 8; ++it) {
        const int idx = it * 512 + tid;
        const int colg = idx >> 4;             // 0..255 (2 heads x 128 hd)
        const int tp8  = (idx & 15) * 8;       // packed-row group
        bf16x8 v = *reinterpret_cast<const bf16x8*>(
            lds + colg * 128 + (tp8 ^ ((colg & 7) << 3)));
        const int trow = (tp8 & 63) + ((tp8 >> 6) << 7) + st * 64;
        const int bh = breg * 16 + (relc >> 7) + (colg >> 7);
        *reinterpret_cast<bf16x8*>(
            XT + (long)bh * (HD_ * S_) + (colg & 127) * S_ + t0 + trow) = v;
      }
      if (st == 0) {
        asm volatile("s_waitcnt lgkmcnt(0)" ::: "memory");
        __builtin_amdgcn_s_barrier();
      }
    }
    return;
  }

  // ---------- normal epilogue (Q region / plain GEMM) ----------
#pragma unroll
  for (int mi = 0; mi < 8; mi++) {
    float vals[4][4];
#pragma unroll
    for (int ni = 0; ni < 4; ni++) {
      const int col = n0 + wn0 + ni * 16 + (lane & 15);
      float bv = 0.0f;
      if constexpr (BIAS) bv = bias[col];
#pragma unroll
      for (int r = 0; r < 4; r++) vals[ni][r] = acc[mi][ni][r] + bv;
    }
    if constexpr (ROPE) {
      if (doRope) {
#pragma unroll
        for (int ni = 0; ni < 2; ni++)
#pragma unroll
          for (int r = 0; r < 4; r++) {
            const int srow = (m0 + wm0 + mi * 16 + (lane >> 4) * 4 + r) & (S_ - 1);
            const int hd = ni * 16 + (lane & 15);
            const float c  = chp[srow * 32 + hd];
            const float sn = shp[srow * 32 + hd];
            const float a  = vals[ni][r], b2 = vals[ni + 2][r];
            vals[ni][r]     = a * c - b2 * sn;
            vals[ni + 2][r] = b2 * c + a * sn;
          }
      }
    }
#pragma unroll
    for (int ni = 0; ni < 4; ni++) {
      const int col = n0 + wn0 + ni * 16 + (lane & 15);
      const long base = (long)(m0 + wm0 + mi * 16 + (lane >> 4) * 4) * lc + col;
#pragma unroll
      for (int r = 0; r < 4; r++) {
        float v = vals[ni][r];
        if constexpr (ACCUM) v += (float)C[base + (long)r * lc];
        C[base + (long)r * lc] = (CT)v;
      }
    }
  }
}

// =====================================================================
// pv256: Ob[b] = mask @ V_b  (K=1024 main loop; SKIPPED when the mask
// is identically zero per the prep-computed flag -- uniform branch,
// general path preserved)  +  Q_b @ W2_b^T (K2=128 tail fused).
// Grid (8,4,8): x=col tile, y=row tile, z=b.
// =====================================================================
__global__ __launch_bounds__(512, 2) void pv256(const bf16* __restrict__ Am,
                                                const bf16* __restrict__ Vt,
                                                const bf16* __restrict__ QKV,
                                                const bf16* __restrict__ W2,
                                                bf16* __restrict__ Ob,
                                                const int* __restrict__ mnz) {
  extern __shared__ __align__(16) bf16 lds[];
  const int z = blockIdx.z;                    // batch b
  const bf16* A  = Am;                         // mask (shared over b)
  const bf16* Bm = Vt + (long)z * (D_ * S_);
  bf16* C = Ob + (long)z * (S_ * D_);
  const long la = S_, lb = S_;
  const int tid  = threadIdx.x;
  const int wid  = tid >> 6;
  const int lane = tid & 63;
  const int wm0 = (wid >> 2) * 128;
  const int wn0 = (wid & 3) * 64;
  const int m0 = blockIdx.y * 256, n0 = blockIdx.x * 256;

  const int rr = lane >> 2;
  const int cc = ((lane & 3) * 8) ^ ((rr & 8) << 1);
  const bf16* agA = A  + (long)(m0 + wid * 16 + rr) * la + cc;
  const bf16* agB = Bm + (long)(n0 + wid * 16 + rr) * lb + cc;

  const int swz  = ((lane >> 4) * 8) ^ ((lane & 8) << 1);
  const int aoff = (wm0 >> 4) * 1024 + (lane & 15) * 32 + swz;
  const int boff = (wn0 >> 4) * 1024 + (lane & 15) * 32 + swz;

  f32x4 acc[8][4] = {};

  const bool hasMask = (*mnz != 0);            // uniform across grid
  if (hasMask) {
    GEMM256_MAIN_LOOP(16);
  }

  // ---------------- K2 tail: acc += Q[.,h*128+e] * W2[h][d][e]^T ----------
  const int h0 = n0 >> 7;
  const int hsel = wn0 >> 7;
  const int a2base = hsel * 16384;
  const int b2base = 32768 + hsel * 8192;
  const int bsub = (wn0 & 64) >> 4;
  const int a2off = (wm0 >> 4) * 1024 + (lane & 15) * 32 + swz;
  const int b2off = (lane & 15) * 32 + swz;

#define STAGE_K2(e0)                                                          \
  { const bf16* qa0 = QKV + (long)(z * S_ + m0 + wid * 16 + rr) * NQKV        \
                      + h0 * 128 + (e0) + cc;                                 \
    gl_lds16(qa0,                       lds + wid * 1024);                    \
    gl_lds16(qa0 + 32,                  lds + wid * 1024 + 512);              \
    gl_lds16(qa0 + 128 * NQKV,          lds + (wid + 8) * 1024);              \
    gl_lds16(qa0 + 128 * NQKV + 32,     lds + (wid + 8) * 1024 + 512);        \
    gl_lds16(qa0 + 128,                 lds + 16384 + wid * 1024);            \
    gl_lds16(qa0 + 160,                 lds + 16384 + wid * 1024 + 512);      \
    gl_lds16(qa0 + 128 * NQKV + 128,    lds + 16384 + (wid + 8) * 1024);      \
    gl_lds16(qa0 + 128 * NQKV + 160,    lds + 16384 + (wid + 8) * 1024 + 512);\
    const bf16* w0 = W2 + (long)(z * 16 + h0) * 16384                         \
                     + (wid * 16 + rr) * 128 + (e0) + cc;                     \
    gl_lds16(w0,                        lds + 32768 + wid * 1024);            \
    gl_lds16(w0 + 32,                   lds + 32768 + wid * 1024 + 512);      \
    gl_lds16(w0 + 16384,                lds + 40960 + wid * 1024);            \
    gl_lds16(w0 + 16384 + 32,           lds + 40960 + wid * 1024 + 512);      }

  __builtin_amdgcn_s_barrier();
  STAGE_K2(0);
#pragma unroll
  for (int step = 0; step < 2; step++) {
    asm volatile("s_waitcnt vmcnt(0)" ::: "memory");
    __builtin_amdgcn_s_barrier();
    __builtin_amdgcn_sched_barrier(0);
    bf16x8 a2[8], b2[4];
#pragma unroll
    for (int ks = 0; ks < 2; ks++) {
#pragma unroll
      for (int mi = 0; mi < 8; mi++)
        a2[mi] = *reinterpret_cast<const bf16x8*>(
            lds + a2base + a2off + mi * 1024 + ks * 512);
#pragma unroll
      for (int ni = 0; ni < 4; ni++)
        b2[ni] = *reinterpret_cast<const bf16x8*>(
            lds + b2base + b2off + (bsub + ni) * 1024 + ks * 512);
      __builtin_amdgcn_s_setprio(1);
#pragma unroll
      for (int mi = 0; mi < 8; mi++)
#pragma unroll
        for (int ni = 0; ni < 4; ni++)
          acc[mi][ni] = __builtin_amdgcn_mfma_f32_16x16x32_bf16(
              a2[mi], b2[ni], acc[mi][ni], 0, 0, 0);
      __builtin_amdgcn_s_setprio(0);
    }
    if (step == 0) {
      asm volatile("s_waitcnt lgkmcnt(0)" ::: "memory");
      __builtin_amdgcn_s_barrier();
      STAGE_K2(64);
    }
  }
#undef STAGE_K2

#pragma unroll
  for (int mi = 0; mi < 8; mi++) {
#pragma unroll
    for (int ni = 0; ni < 4; ni++) {
      const int col = n0 + wn0 + ni * 16 + (lane & 15);
      const long base = (long)(m0 + wm0 + mi * 16 + (lane >> 4) * 4) * D_ + col;
#pragma unroll
      for (int r = 0; r < 4; r++)
        C[base + (long)r * D_] = (bf16)acc[mi][ni][r];
    }
  }
}

// ---------- m97-style 128^2 GEMM (kept for small shapes: W2) ----------
template <typename CT, bool BIAS, bool ACCUM>
__global__ __launch_bounds__(256) void gemm_bt(const bf16* __restrict__ A,
                                               const bf16* __restrict__ Bm,
                                               const float* __restrict__ bias,
                                               CT* __restrict__ C,
                                               int M, int N, int K,
                                               long la, long lb, long lc,
                                               long za, long zb, long zc) {
  __shared__ __align__(16) bf16 As[128 * 32];
  __shared__ __align__(16) bf16 Bs[128 * 32];
  const int z = blockIdx.z;
  A  += (long)z * za;
  Bm += (long)z * zb;
  C  += (long)z * zc;
  const int tid = threadIdx.x;
  const int w = tid >> 6, l = tid & 63;
  const int wm = (w & 1) * 64, wn = (w >> 1) * 64;
  const int m0 = blockIdx.y * 128, n0 = blockIdx.x * 128;
  const int lr = l & 15, lk = (l >> 4) * 8;
  const int er = (l >> 4) * 4;

  const bf16* ag = A  + (long)(m0 + (tid >> 2)) * la + (tid & 3) * 8;
  const bf16* bg = Bm + (long)(n0 + (tid >> 2)) * lb + (tid & 3) * 8;
  bf16* al = As + (w * 16) * 32;
  bf16* bl = Bs + (w * 16) * 32;

  f32x4 acc[4][4] = {};

  for (int k0 = 0; k0 < K; k0 += 32) {
    gl_lds16(ag + k0,            al);
    gl_lds16(ag + 64 * la + k0,  al + 64 * 32);
    gl_lds16(bg + k0,            bl);
    gl_lds16(bg + 64 * lb + k0,  bl + 64 * 32);
    __syncthreads();
    bf16x8 afr[4], bfr[4];
#pragma unroll
    for (int mi = 0; mi < 4; mi++)
      afr[mi] = *reinterpret_cast<const bf16x8*>(As + (wm + mi * 16 + lr) * 32 + lk);
#pragma unroll
    for (int ni = 0; ni < 4; ni++)
      bfr[ni] = *reinterpret_cast<const bf16x8*>(Bs + (wn + ni * 16 + lr) * 32 + lk);
#pragma unroll
    for (int mi = 0; mi < 4; mi++)
#pragma unroll
      for (int ni = 0; ni < 4; ni++)
        acc[mi][ni] = __builtin_amdgcn_mfma_f32_16x16x32_bf16(afr[mi], bfr[ni], acc[mi][ni], 0, 0, 0);
    __syncthreads();
  }

#pragma unroll
  for (int mi = 0; mi < 4; mi++) {
#pragma unroll
    for (int ni = 0; ni < 4; ni++) {
      const int col = n0 + wn + ni * 16 + lr;
      float bv = 0.0f;
      if constexpr (BIAS) bv = bias[col];
      const long base = (long)(m0 + wm + mi * 16 + er) * lc + col;
#pragma unroll
      for (int r = 0; r < 4; r++) {
        float v = acc[mi][ni][r] + bv;
        if constexpr (ACCUM) v += (float)C[base + (long)r * lc];
        C[base + (long)r * lc] = (CT)v;
      }
    }
  }
}

extern "C" void kernel_launch(void* const* d_in, const int* in_sizes, int n_in,
                              void* d_out, int out_size, void* d_ws, size_t ws_size,
                              hipStream_t stream) {
  const float* x   = (const float*)d_in[0];
  const float* wq  = (const float*)d_in[1];
  const float* bq  = (const float*)d_in[2];
  const float* wk  = (const float*)d_in[3];
  const float* bk  = (const float*)d_in[4];
  const float* wv  = (const float*)d_in[5];
  const float* bv  = (const float*)d_in[6];
  const float* wo  = (const float*)d_in[7];
  const float* bo  = (const float*)d_in[8];
  const float* ch  = (const float*)d_in[9];
  const float* sh  = (const float*)d_in[10];
  const float* mask = (const float*)d_in[11];
  float* out = (float*)d_out;

  // allow 128 KiB dynamic LDS for the 256^2 kernels
  hipFuncSetAttribute(reinterpret_cast<const void*>(&gemm256<bf16, true, false, true, 1>),
                      hipFuncAttributeMaxDynamicSharedMemorySize, 131072);
  hipFuncSetAttribute(reinterpret_cast<const void*>(&gemm256<float, true, false, false, 0>),
                      hipFuncAttributeMaxDynamicSharedMemorySize, 131072);
  hipFuncSetAttribute(reinterpret_cast<const void*>(&pv256),
                      hipFuncAttributeMaxDynamicSharedMemorySize, 131072);

  char* ws = (char*)d_ws;
  bf16*  QKV   = (bf16*)(ws);                    // 96 MB (only Q region written)
  bf16*  Vt    = (bf16*)(ws + 100663296);        // 32 MB
  bf16*  Kt    = (bf16*)(ws + 134217728);        // 32 MB
  bf16*  wob   = (bf16*)(ws + 167772160);        // 8 MB
  float* bqkv  = (float*)(ws + 176160768);       // 24 KB
  bf16*  maskb = (bf16*)(ws + 176185344);        // 2 MB
  bf16*  W2    = (bf16*)(ws + 178282496);        // 4 MB
  bf16*  Ob    = (bf16*)(ws + 182476800);        // 32 MB
  bf16*  xb    = (bf16*)(ws + 216031232);        // 32 MB (dead after GEMM1)
  bf16*  wqkvb = (bf16*)(ws + 249585664);        // 24 MB (dead after GEMM1)
  int*   mnz   = (int*)(ws + 176183296);         // 4 B flag (gap before maskb)

  initflag<<<1, 1, 0, stream>>>(mnz);

  // fused conversions + bias pack + mask-nonzero vote
  prep<<<33798, 256, 0, stream>>>(x, wq, wk, wv, wo, mask, bq, bk, bv,
                                  xb, wqkvb, wob, maskb, bqkv, mnz);

  // QKV projection + RoPE + fused K/V transpose:
  //   Q region -> QKV (roped); K -> Kt (roped, transposed); V -> Vt
  gemm256<bf16, true, false, true, 1><<<dim3(24, 32, 1), 512, 131072, stream>>>(
      xb, wqkvb, bqkv, QKV, NROW, NQKV, D_,
      (long)D_, (long)D_, (long)NQKV, 0L, 0L, 0L, ch, sh, Kt, Vt);

  // W2[bh][d][e] = sum_t V[t,d] K[t,e]   (128 batches of 128x128xK=1024)
  gemm_bt<bf16, false, false><<<dim3(1, 1, 128), 256, 0, stream>>>(
      Vt, Kt, nullptr, W2, HD_, HD_, S_,
      (long)S_, (long)S_, (long)HD_,
      (long)(HD_ * S_), (long)(HD_ * S_), (long)(HD_ * HD_));

  // Ob = mask @ V (skipped if mask==0) + Q @ W2^T  (8 batches of 1024x2048)
  pv256<<<dim3(8, 4, 8), 512, 131072, stream>>>(maskb, Vt, QKV, W2, Ob, mnz);

  // out = a_sum @ wo^T + bo  (8192 x 2048 x 2048, fp32 output)
  gemm256<float, true, false, false, 0><<<dim3(8, 32, 1), 512, 131072, stream>>>(
      Ob, wob, bo, out, NROW, D_, D_,
      (long)D_, (long)D_, (long)D_, 0L, 0L, 0L, nullptr, nullptr, nullptr, nullptr);
}